// Round 5
// baseline (365.264 us; speedup 1.0000x reference)
//
#include <hip/hip_runtime.h>

typedef __bf16 bf16_t;
typedef __bf16 bf16x8 __attribute__((ext_vector_type(8)));
typedef float f32x4 __attribute__((ext_vector_type(4)));

#define MFMA16(a, b, c) __builtin_amdgcn_mfma_f32_16x16x32_bf16(a, b, c, 0, 0, 0)

#define F_W 128
#define ED 512
#define NH 8
#define HD 64
#define B_NW 512
#define XB_STRIDE 40   // padded bf16 x-tile stride (conflict-free, reg-staged)

typedef const __attribute__((address_space(1))) void gvoid_t;
typedef __attribute__((address_space(3))) void lvoid_t;
__device__ __forceinline__ void gload16(const void* g, void* l) {
    __builtin_amdgcn_global_load_lds((gvoid_t*)g, (lvoid_t*)l, 16, 0, 0);
}

// ---------------- prep: transpose + convert weights to bf16 ----------------
__global__ __launch_bounds__(256) void prep_kernel(
    const float* __restrict__ qkv_w,   // [512][1536]
    const float* __restrict__ proj_w,  // [512][512]
    bf16_t* __restrict__ qkv_wt,       // [1536][512]
    bf16_t* __restrict__ proj_wt) {    // [512][512]
    int idx = blockIdx.x * 256 + threadIdx.x;
    if (idx < 1536 * 512) {
        int n = idx >> 9, k = idx & 511;
        qkv_wt[idx] = (bf16_t)qkv_w[k * 1536 + n];
    }
    if (idx < 512 * 512) {
        int n = idx >> 9, k = idx & 511;
        proj_wt[idx] = (bf16_t)proj_w[k * 512 + n];
    }
}

// ---------------- fused QKV projection + windowed attention ----------------
// Block per (window, head), XCD-remapped (T1). 256 threads = 4 waves.
// Phase A: 2x2 wave grid (wave wm,wn owns M=64 x N=96), double-buffered
// 1-barrier-per-kc pipeline. LDS (48 KB):
//   staging: xb0 [0,10240) xb1 [10240,20480)  bf16[128][40] padded (reg-staged)
//            wb0 [20480,32768) wb1 [32768,45056) bf16[192][32] swz (gload_lds)
//   post-A:  q [0,16K) [128][64] swz8 | k [16K,32K) | vt [32K,48K) [64][128] swz16
//   post-B:  p [0,32K) [128][128] swz16
__global__ __launch_bounds__(256, 3) void fused_attn_kernel(
    const float* __restrict__ x,        // [B_NW*F_W][ED] fp32
    const float* __restrict__ adj,      // [8][8][128][128] fp32
    const float* __restrict__ qkv_b,    // [1536]
    const bf16_t* __restrict__ qkv_wt,  // [1536][512] bf16 (n-major)
    bf16_t* __restrict__ attn_out) {    // [B_NW*F_W][ED] bf16
    __shared__ __align__(16) char smem[49152];
    bf16_t* xb0 = (bf16_t*)smem;                // [128][40]
    bf16_t* xb1 = (bf16_t*)(smem + 10240);
    bf16_t* wb0 = (bf16_t*)(smem + 20480);      // [192][32]
    bf16_t* wb1 = (bf16_t*)(smem + 32768);
    bf16_t* q_lds  = (bf16_t*)smem;             // [128][64]
    bf16_t* k_lds  = (bf16_t*)(smem + 16384);   // [128][64]
    bf16_t* p_lds  = (bf16_t*)smem;             // [128][128]
    bf16_t* vt_lds = (bf16_t*)(smem + 32768);   // [64][128]

    const int tid  = threadIdx.x;
    const int wave = tid >> 6;
    const int lane = tid & 63;
    const int lrow = lane & 15;
    const int lgrp = lane >> 4;
    const int wm = wave >> 1;   // Phase A 2x2 wave grid
    const int wn = wave & 1;
    // XCD-aware decode (bijective over [0,4096))
    const int bid = blockIdx.x;
    const int w = (bid & 7) * 64 + (bid >> 6);
    const int h = (bid >> 3) & 7;
    const int bidx = bid & 7;

    const float* xw = x + (size_t)w * F_W * ED;

    // x reg-staging: thread -> row tid>>1, col-half (tid&1)*16 of 32-col chunk
    const int xr = tid >> 1;
    const int xc = (tid & 1) * 16;
    // wt gload staging: 1KB chunk = 16 rows x 32 bf16 (preswizzled source col)
    const int wrow_l = lane >> 2;
    const int wcol_l = (((lane & 3) * 8)) ^ ((wrow_l & 3) << 3);

    // ---------------- Phase A: QKV GEMM (M=128, N=192, K=512) --------------
    f32x4 acc[4][6];
#pragma unroll
    for (int mf = 0; mf < 4; ++mf)
#pragma unroll
        for (int nf = 0; nf < 6; ++nf) acc[mf][nf] = (f32x4)0.0f;

    // prologue: stage tile 0 into xb0/wb0
    {
        const float* px = xw + (size_t)xr * ED + xc;
        float4 v0 = *(const float4*)(px + 0);
        float4 v1 = *(const float4*)(px + 4);
        float4 v2 = *(const float4*)(px + 8);
        float4 v3 = *(const float4*)(px + 12);
#pragma unroll
        for (int i = 0; i < 3; ++i) {
            int c = wave * 3 + i;
            int r = c * 16 + wrow_l;
            int n = (r >> 6) * 512 + h * 64 + (r & 63);
            gload16(qkv_wt + (size_t)n * 512 + wcol_l, wb0 + c * 512);
        }
        bf16x8 lo = {(bf16_t)v0.x, (bf16_t)v0.y, (bf16_t)v0.z, (bf16_t)v0.w,
                     (bf16_t)v1.x, (bf16_t)v1.y, (bf16_t)v1.z, (bf16_t)v1.w};
        bf16x8 hi = {(bf16_t)v2.x, (bf16_t)v2.y, (bf16_t)v2.z, (bf16_t)v2.w,
                     (bf16_t)v3.x, (bf16_t)v3.y, (bf16_t)v3.z, (bf16_t)v3.w};
        *(bf16x8*)(xb0 + xr * XB_STRIDE + xc) = lo;
        *(bf16x8*)(xb0 + xr * XB_STRIDE + xc + 8) = hi;
    }
    __syncthreads();

#pragma unroll 2
    for (int kc = 0; kc < 16; ++kc) {
        bf16_t* xbc = (kc & 1) ? xb1 : xb0;
        bf16_t* xbn = (kc & 1) ? xb0 : xb1;
        bf16_t* wbc = (kc & 1) ? wb1 : wb0;
        bf16_t* wbn = (kc & 1) ? wb0 : wb1;
        float4 v0, v1, v2, v3;
        // 1. issue next-tile loads (x regs first, then gloads -> smaller waits)
        if (kc < 15) {
            const int k1 = (kc + 1) * 32;
            const float* px = xw + (size_t)xr * ED + k1 + xc;
            v0 = *(const float4*)(px + 0);
            v1 = *(const float4*)(px + 4);
            v2 = *(const float4*)(px + 8);
            v3 = *(const float4*)(px + 12);
#pragma unroll
            for (int i = 0; i < 3; ++i) {
                int c = wave * 3 + i;
                int r = c * 16 + wrow_l;
                int n = (r >> 6) * 512 + h * 64 + (r & 63);
                gload16(qkv_wt + (size_t)n * 512 + k1 + wcol_l, wbn + c * 512);
            }
        }
        // 2. compute current tile (wave tile M=64 x N=96)
        bf16x8 a[4], b[6];
#pragma unroll
        for (int mf = 0; mf < 4; ++mf) {
            int row = wm * 64 + mf * 16 + lrow;
            a[mf] = *(const bf16x8*)(xbc + row * XB_STRIDE + lgrp * 8);
        }
#pragma unroll
        for (int nf = 0; nf < 6; ++nf) {
            int rw = wn * 96 + nf * 16 + lrow;
            b[nf] = *(const bf16x8*)(wbc + rw * 32 + ((lgrp * 8) ^ ((rw & 3) << 3)));
        }
#pragma unroll
        for (int mf = 0; mf < 4; ++mf)
#pragma unroll
            for (int nf = 0; nf < 6; ++nf)
                acc[mf][nf] = MFMA16(a[mf], b[nf], acc[mf][nf]);
        // 3. finish staging next x tile
        if (kc < 15) {
            bf16x8 lo = {(bf16_t)v0.x, (bf16_t)v0.y, (bf16_t)v0.z, (bf16_t)v0.w,
                         (bf16_t)v1.x, (bf16_t)v1.y, (bf16_t)v1.z, (bf16_t)v1.w};
            bf16x8 hi = {(bf16_t)v2.x, (bf16_t)v2.y, (bf16_t)v2.z, (bf16_t)v2.w,
                         (bf16_t)v3.x, (bf16_t)v3.y, (bf16_t)v3.z, (bf16_t)v3.w};
            *(bf16x8*)(xbn + xr * XB_STRIDE + xc) = lo;
            *(bf16x8*)(xbn + xr * XB_STRIDE + xc + 8) = hi;
        }
        // 4. single barrier per tile (drains vmcnt + lgkmcnt)
        __syncthreads();
    }

    // --- mask prefetch (Phase B rows use the 1D wave tiling: 32 rows/wave) ---
    const float* mbase = adj + ((size_t)(bidx * NH + h)) * F_W * F_W;
    float mv[2][4][8];
#pragma unroll
    for (int mf = 0; mf < 2; ++mf)
#pragma unroll
        for (int j = 0; j < 4; ++j) {
            int row = wave * 32 + mf * 16 + lgrp * 4 + j;
            const float* mrow = mbase + (size_t)row * F_W;
#pragma unroll
            for (int nf = 0; nf < 8; ++nf) mv[mf][j][nf] = mrow[nf * 16 + lrow];
        }

    // ------------- write Q (scaled), K, V^T to LDS with bias ---------------
    // acc col c = wn*96 + nf*16 + lrow; s = c>>6 (0=Q,1=K,2=V); d = c&63
#pragma unroll
    for (int mf = 0; mf < 4; ++mf) {
#pragma unroll
        for (int nf = 0; nf < 6; ++nf) {
            int c = wn * 96 + nf * 16 + lrow;
            int s = c >> 6;
            int d = c & 63;
            float bias = qkv_b[s * 512 + h * 64 + d];
#pragma unroll
            for (int j = 0; j < 4; ++j) {
                int r = wm * 64 + mf * 16 + lgrp * 4 + j;
                float val = acc[mf][nf][j] + bias;
                if (s == 0)      q_lds[r * 64 + (d ^ ((r & 7) << 3))] = (bf16_t)(val * 0.125f);
                else if (s == 1) k_lds[r * 64 + (d ^ ((r & 7) << 3))] = (bf16_t)val;
                else             vt_lds[d * 128 + (r ^ ((d & 15) << 3))] = (bf16_t)val;
            }
        }
    }
    __syncthreads();

    // ---------------- Phase B: S = Q @ K^T + mask, softmax ------------------
    f32x4 sacc[2][8];
#pragma unroll
    for (int mf = 0; mf < 2; ++mf)
#pragma unroll
        for (int nf = 0; nf < 8; ++nf) sacc[mf][nf] = (f32x4)0.0f;

#pragma unroll
    for (int kb = 0; kb < 2; ++kb) {
        bf16x8 a[2], b[8];
#pragma unroll
        for (int mf = 0; mf < 2; ++mf) {
            int row = wave * 32 + mf * 16 + lrow;
            a[mf] = *(const bf16x8*)(q_lds + row * 64 + ((kb * 32 + lgrp * 8) ^ ((row & 7) << 3)));
        }
#pragma unroll
        for (int nf = 0; nf < 8; ++nf) {
            int row = nf * 16 + lrow;
            b[nf] = *(const bf16x8*)(k_lds + row * 64 + ((kb * 32 + lgrp * 8) ^ ((row & 7) << 3)));
        }
#pragma unroll
        for (int mf = 0; mf < 2; ++mf)
#pragma unroll
            for (int nf = 0; nf < 8; ++nf)
                sacc[mf][nf] = MFMA16(a[mf], b[nf], sacc[mf][nf]);
    }

    // mask add (prefetched) + row softmax (registers + shfl only)
#pragma unroll
    for (int mf = 0; mf < 2; ++mf) {
#pragma unroll
        for (int j = 0; j < 4; ++j) {
            float mx = -1e30f;
#pragma unroll
            for (int nf = 0; nf < 8; ++nf) {
                sacc[mf][nf][j] += mv[mf][j][nf];
                mx = fmaxf(mx, sacc[mf][nf][j]);
            }
#pragma unroll
            for (int d = 1; d < 16; d <<= 1) mx = fmaxf(mx, __shfl_xor(mx, d));
            float sum = 0.f;
#pragma unroll
            for (int nf = 0; nf < 8; ++nf) {
                float p = exp2f((sacc[mf][nf][j] - mx) * 1.44269504f);
                sacc[mf][nf][j] = p;
                sum += p;
            }
#pragma unroll
            for (int d = 1; d < 16; d <<= 1) sum += __shfl_xor(sum, d);
            float r = 1.0f / sum;
#pragma unroll
            for (int nf = 0; nf < 8; ++nf) sacc[mf][nf][j] *= r;
        }
    }
    __syncthreads();  // q/k reads done; overwrite with P
#pragma unroll
    for (int mf = 0; mf < 2; ++mf)
#pragma unroll
        for (int nf = 0; nf < 8; ++nf)
#pragma unroll
            for (int j = 0; j < 4; ++j) {
                int row = wave * 32 + mf * 16 + lgrp * 4 + j;
                int col = nf * 16 + lrow;
                p_lds[row * 128 + (col ^ ((row & 15) << 3))] = (bf16_t)sacc[mf][nf][j];
            }
    __syncthreads();

    // ---------------- Phase C: O = P @ V (M=128, N=64, K=128) --------------
    f32x4 oacc[2][4];
#pragma unroll
    for (int mf = 0; mf < 2; ++mf)
#pragma unroll
        for (int nf = 0; nf < 4; ++nf) oacc[mf][nf] = (f32x4)0.0f;

#pragma unroll
    for (int kb = 0; kb < 4; ++kb) {
        bf16x8 a[2], b[4];
#pragma unroll
        for (int mf = 0; mf < 2; ++mf) {
            int row = wave * 32 + mf * 16 + lrow;
            a[mf] = *(const bf16x8*)(p_lds + row * 128 + ((kb * 32 + lgrp * 8) ^ ((row & 15) << 3)));
        }
#pragma unroll
        for (int nf = 0; nf < 4; ++nf) {
            int d = nf * 16 + lrow;
            b[nf] = *(const bf16x8*)(vt_lds + d * 128 + ((kb * 32 + lgrp * 8) ^ ((d & 15) << 3)));
        }
#pragma unroll
        for (int mf = 0; mf < 2; ++mf)
#pragma unroll
            for (int nf = 0; nf < 4; ++nf)
                oacc[mf][nf] = MFMA16(a[mf], b[nf], oacc[mf][nf]);
    }

    bf16_t* obase = attn_out + (size_t)w * F_W * ED + h * HD;
#pragma unroll
    for (int mf = 0; mf < 2; ++mf)
#pragma unroll
        for (int nf = 0; nf < 4; ++nf)
#pragma unroll
            for (int j = 0; j < 4; ++j) {
                int row = wave * 32 + mf * 16 + lgrp * 4 + j;
                obase[(size_t)row * ED + nf * 16 + lrow] = (bf16_t)oacc[mf][nf][j];
            }
}

// ---------------- output projection GEMM: [65536,512]@[512,512]+b ----------
__global__ __launch_bounds__(256) void proj_kernel(
    const bf16_t* __restrict__ a_g,   // attn_out [65536][512] bf16
    const bf16_t* __restrict__ bt_g,  // proj_wt  [512][512] bf16 (n-major)
    const float* __restrict__ bias,   // [512]
    float* __restrict__ out) {        // [65536][512] fp32
    __shared__ __align__(16) bf16_t sm[8192];
    bf16_t* a_s = sm;         // [128][32]
    bf16_t* b_s = sm + 4096;  // [128][32]
    const int tid = threadIdx.x;
    const int wave = tid >> 6, lane = tid & 63;
    const int lrow = lane & 15, lgrp = lane >> 4;
    const int bid = blockIdx.x;                        // [0,2048)
    const int mtile = (bid & 7) * 64 + (bid >> 5);     // bijective remap
    const int ntile = (bid >> 3) & 3;
    const size_t m0 = (size_t)mtile * 128;
    const int n0 = ntile * 128;
    const int wrow_l = lane >> 2;
    const int wcol_l = ((((lane & 3) * 8)) ^ ((wrow_l & 3) << 3));

    f32x4 acc[2][8];
#pragma unroll
    for (int mf = 0; mf < 2; ++mf)
#pragma unroll
        for (int nf = 0; nf < 8; ++nf) acc[mf][nf] = (f32x4)0.0f;

    for (int kc = 0; kc < 16; ++kc) {
        const int k0 = kc * 32;
        __syncthreads();
#pragma unroll
        for (int i = 0; i < 2; ++i) {
            int c = wave * 2 + i;
            gload16(a_g + (m0 + c * 16 + wrow_l) * 512 + k0 + wcol_l, a_s + c * 512);
            gload16(bt_g + (size_t)(n0 + c * 16 + wrow_l) * 512 + k0 + wcol_l, b_s + c * 512);
        }
        __syncthreads();
        bf16x8 a[2], b[8];
#pragma unroll
        for (int mf = 0; mf < 2; ++mf) {
            int row = wave * 32 + mf * 16 + lrow;
            a[mf] = *(const bf16x8*)(a_s + row * 32 + ((lgrp * 8) ^ ((row & 3) << 3)));
        }
#pragma unroll
        for (int nf = 0; nf < 8; ++nf) {
            int row = nf * 16 + lrow;
            b[nf] = *(const bf16x8*)(b_s + row * 32 + ((lgrp * 8) ^ ((row & 3) << 3)));
        }
#pragma unroll
        for (int mf = 0; mf < 2; ++mf)
#pragma unroll
            for (int nf = 0; nf < 8; ++nf)
                acc[mf][nf] = MFMA16(a[mf], b[nf], acc[mf][nf]);
    }

#pragma unroll
    for (int nf = 0; nf < 8; ++nf) {
        int col = n0 + nf * 16 + lrow;
        float bv = bias[col];
#pragma unroll
        for (int mf = 0; mf < 2; ++mf)
#pragma unroll
            for (int j = 0; j < 4; ++j) {
                size_t row = m0 + wave * 32 + mf * 16 + lgrp * 4 + j;
                out[row * 512 + col] = acc[mf][nf][j] + bv;
            }
    }
}

extern "C" void kernel_launch(void* const* d_in, const int* in_sizes, int n_in,
                              void* d_out, int out_size, void* d_ws, size_t ws_size,
                              hipStream_t stream) {
    const float* x      = (const float*)d_in[0];
    const float* adj    = (const float*)d_in[1];
    const float* qkv_w  = (const float*)d_in[2];
    const float* qkv_b  = (const float*)d_in[3];
    const float* proj_w = (const float*)d_in[4];
    const float* proj_b = (const float*)d_in[5];
    float* out = (float*)d_out;

    bf16_t* attn_out = (bf16_t*)d_ws;
    bf16_t* qkv_wt   = attn_out + (size_t)B_NW * F_W * ED;
    bf16_t* proj_wt  = qkv_wt + 1536 * 512;

    prep_kernel<<<3072, 256, 0, stream>>>(qkv_w, proj_w, qkv_wt, proj_wt);
    fused_attn_kernel<<<B_NW * NH, 256, 0, stream>>>(x, adj, qkv_b, qkv_wt, attn_out);
    proj_kernel<<<(B_NW * F_W / 128) * (ED / 128), 256, 0, stream>>>(attn_out, proj_wt, proj_b, out);
}

// Round 6
// 330.742 us; speedup vs baseline: 1.1044x; 1.1044x over previous
//
#include <hip/hip_runtime.h>

typedef __bf16 bf16_t;
typedef __bf16 bf16x8 __attribute__((ext_vector_type(8)));
typedef float f32x4 __attribute__((ext_vector_type(4)));

#define MFMA16(a, b, c) __builtin_amdgcn_mfma_f32_16x16x32_bf16(a, b, c, 0, 0, 0)

#define F_W 128
#define ED 512
#define NH 8
#define HD 64
#define B_NW 512
#define NTOK 65536

typedef const __attribute__((address_space(1))) void gvoid_t;
typedef __attribute__((address_space(3))) void lvoid_t;
__device__ __forceinline__ void gload16(const void* g, void* l) {
    __builtin_amdgcn_global_load_lds((gvoid_t*)g, (lvoid_t*)l, 16, 0, 0);
}

// ---------------- prep: transpose + convert weights to bf16 ----------------
__global__ __launch_bounds__(256) void prep_kernel(
    const float* __restrict__ qkv_w,   // [512][1536]
    const float* __restrict__ proj_w,  // [512][512]
    bf16_t* __restrict__ qkv_wt,       // [1536][512]
    bf16_t* __restrict__ proj_wt) {    // [512][512]
    int idx = blockIdx.x * 256 + threadIdx.x;
    if (idx < 1536 * 512) {
        int n = idx >> 9, k = idx & 511;
        qkv_wt[idx] = (bf16_t)qkv_w[k * 1536 + n];
    }
    if (idx < 512 * 512) {
        int n = idx >> 9, k = idx & 511;
        proj_wt[idx] = (bf16_t)proj_w[k * 512 + n];
    }
}

// ---------------- K2: QKV GEMM [65536,512]x[512,1536] -----------------------
// 128x128 tiles, grid 512 m-tiles x 12 n-tiles = 6144 blocks (XCD-remapped:
// XCD owns contiguous m-range; 12 n-tiles of one m-tile consecutive).
// n-tiles 0..3 -> Q (scaled 0.125), 4..7 -> K, 8..11 -> V (written TRANSPOSED
// per (window,head) to vt_ws via LDS bounce).
// LDS 24 KB -> 4 blocks/CU (VGPR<=128), 16 waves/CU.
__global__ __launch_bounds__(256, 4) void qkv_gemm_kernel(
    const float* __restrict__ x,        // [NTOK][512] fp32
    const bf16_t* __restrict__ qkv_wt,  // [1536][512] bf16 (n-major)
    const float* __restrict__ qkv_b,    // [1536]
    bf16_t* qk_ws,                      // [NTOK][1024]  Q(scaled)|K
    bf16_t* vt_ws) {                    // [4096][64][128]  V^T per (w,h)
    __shared__ __align__(16) char sm[24576];
    float*  x_s = (float*)sm;             // [128][32] f32 swz
    bf16_t* w_s = (bf16_t*)(sm + 16384);  // [128][32] bf16 swz
    bf16_t* tb  = (bf16_t*)sm;            // [128][72] epilogue transpose (aliases)

    const int tid = threadIdx.x;
    const int wave = tid >> 6, lane = tid & 63;
    const int lrow = lane & 15, lgrp = lane >> 4;
    const int bid = blockIdx.x;
    const int idx = bid >> 3;
    const int mt_l = idx / 12;
    const int nt = idx - mt_l * 12;
    const int mtile = (bid & 7) * 64 + mt_l;   // == window index
    const size_t m0 = (size_t)mtile * 128;
    const int n0 = nt * 128;

    // staging source mappings (preswizzled cols)
    const int xrow_l = lane >> 3;                                   // 8 rows/KB
    const int xcol_l = ((lane & 7) * 4) ^ ((xrow_l & 7) << 2);      // f32 elems
    const int wrow_l = lane >> 2;                                   // 16 rows/KB
    const int wcol_l = ((lane & 3) * 8) ^ ((wrow_l & 3) << 3);      // bf16 elems

    f32x4 acc[2][8];
#pragma unroll
    for (int mf = 0; mf < 2; ++mf)
#pragma unroll
        for (int nf = 0; nf < 8; ++nf) acc[mf][nf] = (f32x4)0.0f;

    for (int kc = 0; kc < 16; ++kc) {
        const int k0 = kc * 32;
        __syncthreads();
#pragma unroll
        for (int i = 0; i < 4; ++i) {  // x: 16 KB = 16 chunks
            int c = wave * 4 + i;
            gload16(x + (m0 + c * 8 + xrow_l) * 512 + k0 + xcol_l, x_s + c * 256);
        }
#pragma unroll
        for (int i = 0; i < 2; ++i) {  // w: 8 KB = 8 chunks
            int c = wave * 2 + i;
            int n = n0 + c * 16 + wrow_l;
            gload16(qkv_wt + (size_t)n * 512 + k0 + wcol_l, w_s + c * 512);
        }
        __syncthreads();

        bf16x8 a[2], b[8];
#pragma unroll
        for (int mf = 0; mf < 2; ++mf) {
            int row = wave * 32 + mf * 16 + lrow;
            int sw = (row & 7) << 2;
            const float* px = x_s + row * 32;
            f32x4 lo = *(const f32x4*)(px + ((lgrp * 8) ^ sw));
            f32x4 hi = *(const f32x4*)(px + ((lgrp * 8 + 4) ^ sw));
            a[mf] = bf16x8{(bf16_t)lo[0], (bf16_t)lo[1], (bf16_t)lo[2], (bf16_t)lo[3],
                           (bf16_t)hi[0], (bf16_t)hi[1], (bf16_t)hi[2], (bf16_t)hi[3]};
        }
#pragma unroll
        for (int nf = 0; nf < 8; ++nf) {
            int row = nf * 16 + lrow;
            b[nf] = *(const bf16x8*)(w_s + row * 32 + ((lgrp * 8) ^ ((row & 3) << 3)));
        }
#pragma unroll
        for (int mf = 0; mf < 2; ++mf)
#pragma unroll
            for (int nf = 0; nf < 8; ++nf)
                acc[mf][nf] = MFMA16(a[mf], b[nf], acc[mf][nf]);
    }

    if (nt < 8) {
        // Q or K tile: bias, scale Q, write row-major bf16 to qk_ws
        const float scale = (nt < 4) ? 0.125f : 1.0f;
#pragma unroll
        for (int nf = 0; nf < 8; ++nf) {
            int col = n0 + nf * 16 + lrow;            // in [0,1024)
            float bv = qkv_b[col];
#pragma unroll
            for (int mf = 0; mf < 2; ++mf)
#pragma unroll
                for (int j = 0; j < 4; ++j) {
                    int r = wave * 32 + mf * 16 + lgrp * 4 + j;
                    qk_ws[(m0 + r) * 1024 + col] =
                        (bf16_t)((acc[mf][nf][j] + bv) * scale);
                }
        }
    } else {
        // V tile: two head-halves, LDS-bounce transpose -> vt_ws[w*8+h][d][k]
#pragma unroll
        for (int hh = 0; hh < 2; ++hh) {
            int h = (nt - 8) * 2 + hh;
            __syncthreads();
#pragma unroll
            for (int mf = 0; mf < 2; ++mf)
#pragma unroll
                for (int nfl = 0; nfl < 4; ++nfl) {
                    int nf = hh * 4 + nfl;
                    int d = nfl * 16 + lrow;          // [0,64)
                    float bv = qkv_b[n0 + hh * 64 + d];
#pragma unroll
                    for (int j = 0; j < 4; ++j) {
                        int r = wave * 32 + mf * 16 + lgrp * 4 + j;
                        tb[r * 72 + d] = (bf16_t)(acc[mf][nf][j] + bv);
                    }
                }
            __syncthreads();
            // read transposed, write coalesced 64B-per-lane rows
            {
                int d = tid & 63;
                int kh = tid >> 6;                    // 0..3 -> k range kh*32
                bf16_t* outp = vt_ws + ((size_t)(mtile * 8 + h) * 64 + d) * 128 + kh * 32;
#pragma unroll
                for (int o = 0; o < 4; ++o) {
                    bf16x8 v;
#pragma unroll
                    for (int e = 0; e < 8; ++e)
                        v[e] = tb[(kh * 32 + o * 8 + e) * 72 + d];
                    *(bf16x8*)(outp + o * 8) = v;
                }
            }
        }
    }
}

// ---------------- K3: attention-only, block=(window,head), 512 thr ----------
// 8 waves x 16 Q-rows each. LDS 32 KB: k_lds [128][64] swz (gload preswz),
// vt_lds [64][128] swz (gload preswz); P in 32-col chunks in k's dead space.
// Q direct global->regs. O overwrites the Q-columns of qk_ws.
__global__ __launch_bounds__(512, 4) void attn_kernel(
    bf16_t* qk_ws,                      // [NTOK][1024] (Q|K; O written to Q cols)
    const bf16_t* __restrict__ vt_ws,   // [4096][64][128]
    const float* __restrict__ adj) {    // [8][8][128][128]
    __shared__ __align__(16) char sm[32768];
    bf16_t* k_lds  = (bf16_t*)sm;             // [128][64]
    bf16_t* vt_lds = (bf16_t*)(sm + 16384);   // [64][128]
    bf16_t* pbuf   = (bf16_t*)sm;             // [128][40] (aliases k after B)

    const int tid = threadIdx.x;
    const int wave = tid >> 6, lane = tid & 63;
    const int lrow = lane & 15, lgrp = lane >> 4;
    const int bid = blockIdx.x;
    const int w = (bid & 7) * 64 + (bid >> 6);
    const int h = (bid >> 3) & 7;
    const int bidx = bid & 7;

    bf16_t* qrow = qk_ws + (size_t)w * 128 * 1024;

    // stage K [128][64]: 16 chunks of 8 rows; preswz col for swz8 reads
    {
        const int krow_l = lane >> 3;
        const int kcol_l = ((lane & 7) * 8) ^ ((krow_l & 7) << 3);
#pragma unroll
        for (int i = 0; i < 2; ++i) {
            int c = wave * 2 + i;
            gload16(qrow + (size_t)(c * 8 + krow_l) * 1024 + 512 + h * 64 + kcol_l,
                    k_lds + c * 512);
        }
    }
    // stage V^T [64][128]: 16 chunks of 4 rows; preswz col ((d&7)<<3)
    {
        const bf16_t* vtb = vt_ws + (size_t)(w * 8 + h) * 64 * 128;
        const int vrow_l = lane >> 4;                 // 0..3 within chunk
#pragma unroll
        for (int i = 0; i < 2; ++i) {
            int c = wave * 2 + i;
            int d = c * 4 + vrow_l;
            int vcol = ((lane & 15) * 8) ^ ((d & 7) << 3);
            gload16(vtb + (size_t)d * 128 + vcol, vt_lds + c * 512);
        }
    }
    // Q -> regs (own 16 rows)
    bf16x8 aq[2];
    {
        int row = wave * 16 + lrow;
#pragma unroll
        for (int kb = 0; kb < 2; ++kb)
            aq[kb] = *(const bf16x8*)(qrow + (size_t)row * 1024 + h * 64 + kb * 32 + lgrp * 8);
    }
    __syncthreads();

    // ---------------- Phase B: S = Q @ K^T ----------------------------------
    f32x4 sacc[8];
#pragma unroll
    for (int nf = 0; nf < 8; ++nf) sacc[nf] = (f32x4)0.0f;
#pragma unroll
    for (int kb = 0; kb < 2; ++kb) {
        bf16x8 b[8];
#pragma unroll
        for (int nf = 0; nf < 8; ++nf) {
            int row = nf * 16 + lrow;
            b[nf] = *(const bf16x8*)(k_lds + row * 64 + ((kb * 32 + lgrp * 8) ^ ((row & 7) << 3)));
        }
#pragma unroll
        for (int nf = 0; nf < 8; ++nf)
            sacc[nf] = MFMA16(aq[kb], b[nf], sacc[nf]);
    }

    // mask add + row softmax (16 rows per wave, exact, regs + shfl)
    const float* mbase = adj + ((size_t)(bidx * NH + h)) * F_W * F_W;
#pragma unroll
    for (int j = 0; j < 4; ++j) {
        int row = wave * 16 + lgrp * 4 + j;
        const float* mrow = mbase + (size_t)row * F_W;
        float mx = -1e30f;
#pragma unroll
        for (int nf = 0; nf < 8; ++nf) {
            sacc[nf][j] += mrow[nf * 16 + lrow];
            mx = fmaxf(mx, sacc[nf][j]);
        }
#pragma unroll
        for (int d = 1; d < 16; d <<= 1) mx = fmaxf(mx, __shfl_xor(mx, d));
        float sum = 0.f;
#pragma unroll
        for (int nf = 0; nf < 8; ++nf) {
            float p = exp2f((sacc[nf][j] - mx) * 1.44269504f);
            sacc[nf][j] = p;
            sum += p;
        }
#pragma unroll
        for (int d = 1; d < 16; d <<= 1) sum += __shfl_xor(sum, d);
        float r = 1.0f / sum;
#pragma unroll
        for (int nf = 0; nf < 8; ++nf) sacc[nf][j] *= r;
    }
    __syncthreads();  // all waves done with k_lds -> pbuf may overwrite

    // ---------------- Phase C: O = P @ V, chunked over K (4 x 32) -----------
    f32x4 oacc[4];
#pragma unroll
    for (int nf = 0; nf < 4; ++nf) oacc[nf] = (f32x4)0.0f;

#pragma unroll
    for (int kb = 0; kb < 4; ++kb) {
        // write P chunk [128 rows][32 k] (own 16 rows; stride 40 = conflict-free)
#pragma unroll
        for (int nn = 0; nn < 2; ++nn) {
            int nf = kb * 2 + nn;
            int kk = nn * 16 + lrow;
#pragma unroll
            for (int j = 0; j < 4; ++j) {
                int r = wave * 16 + lgrp * 4 + j;
                pbuf[r * 40 + kk] = (bf16_t)(sacc[nf][j]);
            }
        }
        __syncthreads();
        bf16x8 a = *(const bf16x8*)(pbuf + (wave * 16 + lrow) * 40 + lgrp * 8);
        bf16x8 b[4];
#pragma unroll
        for (int nf = 0; nf < 4; ++nf) {
            int d = nf * 16 + lrow;
            b[nf] = *(const bf16x8*)(vt_lds + d * 128 + ((kb * 32 + lgrp * 8) ^ ((d & 7) << 3)));
        }
#pragma unroll
        for (int nf = 0; nf < 4; ++nf)
            oacc[nf] = MFMA16(a, b[nf], oacc[nf]);
        __syncthreads();
    }

    // O overwrites Q columns of qk_ws (this block's own region only)
#pragma unroll
    for (int nf = 0; nf < 4; ++nf) {
        int ocol = h * 64 + nf * 16 + lrow;
#pragma unroll
        for (int j = 0; j < 4; ++j) {
            int r = wave * 16 + lgrp * 4 + j;
            qrow[(size_t)r * 1024 + ocol] = (bf16_t)oacc[nf][j];
        }
    }
}

// ---------------- K4: output projection [65536,512]@[512,512]+b -------------
// A = attention output living in qk_ws cols 0..511 (row stride 1024).
__global__ __launch_bounds__(256) void proj_kernel(
    const bf16_t* __restrict__ a_g,   // [NTOK][1024] (cols 0..511 = O)
    const bf16_t* __restrict__ bt_g,  // proj_wt [512][512] (n-major)
    const float* __restrict__ bias,   // [512]
    float* __restrict__ out) {        // [NTOK][512] fp32
    __shared__ __align__(16) bf16_t sm_[8192];
    bf16_t* a_s = sm_;         // [128][32]
    bf16_t* b_s = sm_ + 4096;  // [128][32]
    const int tid = threadIdx.x;
    const int wave = tid >> 6, lane = tid & 63;
    const int lrow = lane & 15, lgrp = lane >> 4;
    const int bid = blockIdx.x;                        // [0,2048)
    const int mtile = (bid & 7) * 64 + (bid >> 5);     // bijective remap
    const int ntile = (bid >> 3) & 3;
    const size_t m0 = (size_t)mtile * 128;
    const int n0 = ntile * 128;
    const int wrow_l = lane >> 2;
    const int wcol_l = ((lane & 3) * 8) ^ ((wrow_l & 3) << 3);

    f32x4 acc[2][8];
#pragma unroll
    for (int mf = 0; mf < 2; ++mf)
#pragma unroll
        for (int nf = 0; nf < 8; ++nf) acc[mf][nf] = (f32x4)0.0f;

    for (int kc = 0; kc < 16; ++kc) {
        const int k0 = kc * 32;
        __syncthreads();
#pragma unroll
        for (int i = 0; i < 2; ++i) {
            int c = wave * 2 + i;
            gload16(a_g + (m0 + c * 16 + wrow_l) * 1024 + k0 + wcol_l, a_s + c * 512);
            gload16(bt_g + (size_t)(n0 + c * 16 + wrow_l) * 512 + k0 + wcol_l, b_s + c * 512);
        }
        __syncthreads();
        bf16x8 a[2], b[8];
#pragma unroll
        for (int mf = 0; mf < 2; ++mf) {
            int row = wave * 32 + mf * 16 + lrow;
            a[mf] = *(const bf16x8*)(a_s + row * 32 + ((lgrp * 8) ^ ((row & 3) << 3)));
        }
#pragma unroll
        for (int nf = 0; nf < 8; ++nf) {
            int row = nf * 16 + lrow;
            b[nf] = *(const bf16x8*)(b_s + row * 32 + ((lgrp * 8) ^ ((row & 3) << 3)));
        }
#pragma unroll
        for (int mf = 0; mf < 2; ++mf)
#pragma unroll
            for (int nf = 0; nf < 8; ++nf)
                acc[mf][nf] = MFMA16(a[mf], b[nf], acc[mf][nf]);
    }

#pragma unroll
    for (int nf = 0; nf < 8; ++nf) {
        int col = n0 + nf * 16 + lrow;
        float bv = bias[col];
#pragma unroll
        for (int mf = 0; mf < 2; ++mf)
#pragma unroll
            for (int j = 0; j < 4; ++j) {
                size_t row = m0 + wave * 32 + mf * 16 + lgrp * 4 + j;
                out[row * 512 + col] = acc[mf][nf][j] + bv;
            }
    }
}

extern "C" void kernel_launch(void* const* d_in, const int* in_sizes, int n_in,
                              void* d_out, int out_size, void* d_ws, size_t ws_size,
                              hipStream_t stream) {
    const float* x      = (const float*)d_in[0];
    const float* adj    = (const float*)d_in[1];
    const float* qkv_w  = (const float*)d_in[2];
    const float* qkv_b  = (const float*)d_in[3];
    const float* proj_w = (const float*)d_in[4];
    const float* proj_b = (const float*)d_in[5];
    float* out = (float*)d_out;

    // ws layout: qk_ws 134.2MB | vt_ws 67.1MB | qkv_wt 1.5MB | proj_wt 0.5MB
    bf16_t* qk_ws   = (bf16_t*)d_ws;
    bf16_t* vt_ws   = qk_ws + (size_t)NTOK * 1024;
    bf16_t* qkv_wt  = vt_ws + (size_t)4096 * 64 * 128;
    bf16_t* proj_wt = qkv_wt + 1536 * 512;

    prep_kernel<<<3072, 256, 0, stream>>>(qkv_w, proj_w, qkv_wt, proj_wt);
    qkv_gemm_kernel<<<6144, 256, 0, stream>>>(x, qkv_wt, qkv_b, qk_ws, vt_ws);
    attn_kernel<<<4096, 512, 0, stream>>>(qk_ws, vt_ws, adj);
    proj_kernel<<<2048, 256, 0, stream>>>(qk_ws, proj_wt, proj_b, out);
}

// Round 7
// 317.249 us; speedup vs baseline: 1.1513x; 1.0425x over previous
//
#include <hip/hip_runtime.h>

typedef __bf16 bf16_t;
typedef __bf16 bf16x8 __attribute__((ext_vector_type(8)));
typedef float f32x4 __attribute__((ext_vector_type(4)));

#define MFMA16(a, b, c) __builtin_amdgcn_mfma_f32_16x16x32_bf16(a, b, c, 0, 0, 0)

#define F_W 128
#define ED 512
#define NH 8
#define HD 64
#define B_NW 512
#define NTOK 65536

typedef const __attribute__((address_space(1))) void gvoid_t;
typedef __attribute__((address_space(3))) void lvoid_t;
__device__ __forceinline__ void gload16(const void* g, void* l) {
    __builtin_amdgcn_global_load_lds((gvoid_t*)g, (lvoid_t*)l, 16, 0, 0);
}

// swizzle for [row][32] bf16 tiles (row stride 64B = 16 banks):
// even/odd rows split bank halves; spread row-pairs over the 4 16B slots.
__device__ __forceinline__ int swz32(int row) { return ((row >> 1) & 3) << 3; }

// ---------------- prep: weights -> bf16 transposed --------------------------
__global__ __launch_bounds__(256) void prep_kernel(
    const float* __restrict__ qkv_w,   // [512][1536]
    const float* __restrict__ proj_w,  // [512][512]
    bf16_t* __restrict__ qkv_wt,       // [1536][512]
    bf16_t* __restrict__ proj_wt) {    // [512][512]
    int idx = blockIdx.x * 256 + threadIdx.x;
    if (idx < 1536 * 512) {
        int n = idx >> 9, k = idx & 511;
        qkv_wt[idx] = (bf16_t)qkv_w[k * 1536 + n];
    }
    if (idx < 512 * 512) {
        int n = idx >> 9, k = idx & 511;
        proj_wt[idx] = (bf16_t)proj_w[k * 512 + n];
    }
}

// ---------------- prep_x: x fp32 -> bf16 (into d_out scratch) ---------------
__global__ __launch_bounds__(256) void prep_x_kernel(
    const float* __restrict__ x, bf16_t* __restrict__ xbf) {
    size_t i = ((size_t)blockIdx.x * 256 + threadIdx.x) * 8;
    float4 v0 = *(const float4*)(x + i);
    float4 v1 = *(const float4*)(x + i + 4);
    bf16x8 o = {(bf16_t)v0.x, (bf16_t)v0.y, (bf16_t)v0.z, (bf16_t)v0.w,
                (bf16_t)v1.x, (bf16_t)v1.y, (bf16_t)v1.z, (bf16_t)v1.w};
    *(bf16x8*)(xbf + i) = o;
}

// ---------------- K2: QKV GEMM [65536,512]x[512,1536] -----------------------
// 128x128 tiles, 2x2 wave grid (wave tile 64x64). XCD-remapped grid.
// n-tiles 0..3 -> Q (x0.125), 4..7 -> K, 8..11 -> V (transposed to vt_ws).
__global__ __launch_bounds__(256, 4) void qkv_gemm_kernel(
    const bf16_t* __restrict__ xbf,     // [NTOK][512] bf16
    const bf16_t* __restrict__ qkv_wt,  // [1536][512] bf16 (n-major)
    const float* __restrict__ qkv_b,    // [1536]
    bf16_t* qk_ws,                      // [NTOK][1024]  Q(scaled)|K
    bf16_t* vt_ws) {                    // [4096][64][128]  V^T per (w,h)
    __shared__ __align__(16) char sm[18432];
    bf16_t* x_s = (bf16_t*)sm;             // [128][32] swz
    bf16_t* w_s = (bf16_t*)(sm + 8192);    // [128][32] swz
    bf16_t* tb  = (bf16_t*)sm;             // [128][72] epilogue bounce (aliases)

    const int tid = threadIdx.x;
    const int wave = tid >> 6, lane = tid & 63;
    const int lrow = lane & 15, lgrp = lane >> 4;
    const int wm = wave >> 1, wn = wave & 1;
    const int bid = blockIdx.x;
    const int idx = bid >> 3;
    const int mt_l = idx / 12;
    const int nt = idx - mt_l * 12;
    const int mtile = (bid & 7) * 64 + mt_l;   // == window index
    const size_t m0 = (size_t)mtile * 128;
    const int n0 = nt * 128;

    // staging: 1KB chunk = 16 rows x 32 bf16; lane -> row lane>>2, seg lane&3
    const int row16 = lane >> 2;
    const int scol = ((lane & 3) * 8) ^ swz32(row16);  // preswizzled source col

    f32x4 acc[4][4];
#pragma unroll
    for (int mf = 0; mf < 4; ++mf)
#pragma unroll
        for (int nf = 0; nf < 4; ++nf) acc[mf][nf] = (f32x4)0.0f;

    for (int kc = 0; kc < 16; ++kc) {
        const int k0 = kc * 32;
        __syncthreads();
#pragma unroll
        for (int i = 0; i < 2; ++i) {  // x: 8 chunks
            int c = wave * 2 + i;
            gload16(xbf + (m0 + c * 16 + row16) * 512 + k0 + scol, x_s + c * 512);
        }
#pragma unroll
        for (int i = 0; i < 2; ++i) {  // w: 8 chunks
            int c = wave * 2 + i;
            gload16(qkv_wt + (size_t)(n0 + c * 16 + row16) * 512 + k0 + scol,
                    w_s + c * 512);
        }
        __syncthreads();

        bf16x8 a[4], b[4];
#pragma unroll
        for (int mf = 0; mf < 4; ++mf) {
            int row = wm * 64 + mf * 16 + lrow;
            a[mf] = *(const bf16x8*)(x_s + row * 32 + ((lgrp * 8) ^ swz32(row)));
        }
#pragma unroll
        for (int nf = 0; nf < 4; ++nf) {
            int rw = wn * 64 + nf * 16 + lrow;
            b[nf] = *(const bf16x8*)(w_s + rw * 32 + ((lgrp * 8) ^ swz32(rw)));
        }
#pragma unroll
        for (int mf = 0; mf < 4; ++mf)
#pragma unroll
            for (int nf = 0; nf < 4; ++nf)
                acc[mf][nf] = MFMA16(a[mf], b[nf], acc[mf][nf]);
    }

    if (nt < 8) {
        // Q or K tile: bias, scale Q, row-major bf16 to qk_ws
        const float scale = (nt < 4) ? 0.125f : 1.0f;
#pragma unroll
        for (int nf = 0; nf < 4; ++nf) {
            int col = n0 + wn * 64 + nf * 16 + lrow;   // [0,1024)
            float bv = qkv_b[col];
#pragma unroll
            for (int mf = 0; mf < 4; ++mf)
#pragma unroll
                for (int j = 0; j < 4; ++j) {
                    int r = wm * 64 + mf * 16 + lgrp * 4 + j;
                    qk_ws[(m0 + r) * 1024 + col] =
                        (bf16_t)((acc[mf][nf][j] + bv) * scale);
                }
        }
    } else {
        // V tile = heads (nt-8)*2 + {0,1}; wave's wn selects the head half.
#pragma unroll
        for (int hh = 0; hh < 2; ++hh) {
            int h = (nt - 8) * 2 + hh;
            __syncthreads();   // prior x_s/w_s (or tb) reads complete
            if (wn == hh) {
#pragma unroll
                for (int nf = 0; nf < 4; ++nf) {
                    int d = nf * 16 + lrow;            // [0,64)
                    float bv = qkv_b[n0 + hh * 64 + d];
#pragma unroll
                    for (int mf = 0; mf < 4; ++mf)
#pragma unroll
                        for (int j = 0; j < 4; ++j) {
                            int r = wm * 64 + mf * 16 + lgrp * 4 + j;
                            tb[r * 72 + d] = (bf16_t)(acc[mf][nf][j] + bv);
                        }
                }
            }
            __syncthreads();
            // transpose-read, coalesced write: vt_ws[(mtile*8+h)][d][k]
            {
                int d = tid & 63;
                int kh = tid >> 6;                     // k range kh*32
                bf16_t* outp = vt_ws + ((size_t)(mtile * 8 + h) * 64 + d) * 128 + kh * 32;
#pragma unroll
                for (int o = 0; o < 4; ++o) {
                    bf16x8 v;
#pragma unroll
                    for (int e = 0; e < 8; ++e)
                        v[e] = tb[(kh * 32 + o * 8 + e) * 72 + d];
                    *(bf16x8*)(outp + o * 8) = v;
                }
            }
        }
    }
}

// ---------------- K3: attention-only, block=(window,head), 512 thr ----------
__global__ __launch_bounds__(512, 4) void attn_kernel(
    bf16_t* qk_ws,                      // [NTOK][1024] (Q|K; O -> Q cols)
    const bf16_t* __restrict__ vt_ws,   // [4096][64][128]
    const float* __restrict__ adj) {    // [8][8][128][128]
    __shared__ __align__(16) char sm[32768];
    bf16_t* k_lds  = (bf16_t*)sm;             // [128][64]
    bf16_t* vt_lds = (bf16_t*)(sm + 16384);   // [64][128]
    bf16_t* pbuf   = (bf16_t*)sm;             // [128][40] (aliases k after B)

    const int tid = threadIdx.x;
    const int wave = tid >> 6, lane = tid & 63;
    const int lrow = lane & 15, lgrp = lane >> 4;
    const int bid = blockIdx.x;
    const int w = (bid & 7) * 64 + (bid >> 6);
    const int h = (bid >> 3) & 7;
    const int bidx = bid & 7;

    bf16_t* qrow = qk_ws + (size_t)w * 128 * 1024;

    {
        const int krow_l = lane >> 3;
        const int kcol_l = ((lane & 7) * 8) ^ ((krow_l & 7) << 3);
#pragma unroll
        for (int i = 0; i < 2; ++i) {
            int c = wave * 2 + i;
            gload16(qrow + (size_t)(c * 8 + krow_l) * 1024 + 512 + h * 64 + kcol_l,
                    k_lds + c * 512);
        }
    }
    {
        const bf16_t* vtb = vt_ws + (size_t)(w * 8 + h) * 64 * 128;
        const int vrow_l = lane >> 4;
#pragma unroll
        for (int i = 0; i < 2; ++i) {
            int c = wave * 2 + i;
            int d = c * 4 + vrow_l;
            int vcol = ((lane & 15) * 8) ^ ((d & 7) << 3);
            gload16(vtb + (size_t)d * 128 + vcol, vt_lds + c * 512);
        }
    }
    bf16x8 aq[2];
    {
        int row = wave * 16 + lrow;
#pragma unroll
        for (int kb = 0; kb < 2; ++kb)
            aq[kb] = *(const bf16x8*)(qrow + (size_t)row * 1024 + h * 64 + kb * 32 + lgrp * 8);
    }
    __syncthreads();

    f32x4 sacc[8];
#pragma unroll
    for (int nf = 0; nf < 8; ++nf) sacc[nf] = (f32x4)0.0f;
#pragma unroll
    for (int kb = 0; kb < 2; ++kb) {
        bf16x8 b[8];
#pragma unroll
        for (int nf = 0; nf < 8; ++nf) {
            int row = nf * 16 + lrow;
            b[nf] = *(const bf16x8*)(k_lds + row * 64 + ((kb * 32 + lgrp * 8) ^ ((row & 7) << 3)));
        }
#pragma unroll
        for (int nf = 0; nf < 8; ++nf)
            sacc[nf] = MFMA16(aq[kb], b[nf], sacc[nf]);
    }

    const float* mbase = adj + ((size_t)(bidx * NH + h)) * F_W * F_W;
#pragma unroll
    for (int j = 0; j < 4; ++j) {
        int row = wave * 16 + lgrp * 4 + j;
        const float* mrow = mbase + (size_t)row * F_W;
        float mx = -1e30f;
#pragma unroll
        for (int nf = 0; nf < 8; ++nf) {
            sacc[nf][j] += mrow[nf * 16 + lrow];
            mx = fmaxf(mx, sacc[nf][j]);
        }
#pragma unroll
        for (int d = 1; d < 16; d <<= 1) mx = fmaxf(mx, __shfl_xor(mx, d));
        float sum = 0.f;
#pragma unroll
        for (int nf = 0; nf < 8; ++nf) {
            float p = exp2f((sacc[nf][j] - mx) * 1.44269504f);
            sacc[nf][j] = p;
            sum += p;
        }
#pragma unroll
        for (int d = 1; d < 16; d <<= 1) sum += __shfl_xor(sum, d);
        float r = 1.0f / sum;
#pragma unroll
        for (int nf = 0; nf < 8; ++nf) sacc[nf][j] *= r;
    }
    __syncthreads();

    f32x4 oacc[4];
#pragma unroll
    for (int nf = 0; nf < 4; ++nf) oacc[nf] = (f32x4)0.0f;

#pragma unroll
    for (int kb = 0; kb < 4; ++kb) {
#pragma unroll
        for (int nn = 0; nn < 2; ++nn) {
            int nf = kb * 2 + nn;
            int kk = nn * 16 + lrow;
#pragma unroll
            for (int j = 0; j < 4; ++j) {
                int r = wave * 16 + lgrp * 4 + j;
                pbuf[r * 40 + kk] = (bf16_t)(sacc[nf][j]);
            }
        }
        __syncthreads();
        bf16x8 a = *(const bf16x8*)(pbuf + (wave * 16 + lrow) * 40 + lgrp * 8);
        bf16x8 b[4];
#pragma unroll
        for (int nf = 0; nf < 4; ++nf) {
            int d = nf * 16 + lrow;
            b[nf] = *(const bf16x8*)(vt_lds + d * 128 + ((kb * 32 + lgrp * 8) ^ ((d & 7) << 3)));
        }
#pragma unroll
        for (int nf = 0; nf < 4; ++nf)
            oacc[nf] = MFMA16(a, b[nf], oacc[nf]);
        __syncthreads();
    }

#pragma unroll
    for (int nf = 0; nf < 4; ++nf) {
        int ocol = h * 64 + nf * 16 + lrow;
#pragma unroll
        for (int j = 0; j < 4; ++j) {
            int r = wave * 16 + lgrp * 4 + j;
            qrow[(size_t)r * 1024 + ocol] = (bf16_t)oacc[nf][j];
        }
    }
}

// ---------------- K4: output projection [65536,512]@[512,512]+b -------------
__global__ __launch_bounds__(256, 4) void proj_kernel(
    const bf16_t* __restrict__ a_g,   // [NTOK][1024] (cols 0..511 = O)
    const bf16_t* __restrict__ bt_g,  // proj_wt [512][512] (n-major)
    const float* __restrict__ bias,   // [512]
    float* __restrict__ out) {        // [NTOK][512] fp32
    __shared__ __align__(16) bf16_t sm_[8192];
    bf16_t* a_s = sm_;         // [128][32]
    bf16_t* b_s = sm_ + 4096;  // [128][32]
    const int tid = threadIdx.x;
    const int wave = tid >> 6, lane = tid & 63;
    const int lrow = lane & 15, lgrp = lane >> 4;
    const int wm = wave >> 1, wn = wave & 1;
    const int bid = blockIdx.x;                        // [0,2048)
    const int mtile = (bid & 7) * 64 + (bid >> 5);
    const int ntile = (bid >> 3) & 3;
    const size_t m0 = (size_t)mtile * 128;
    const int n0 = ntile * 128;
    const int row16 = lane >> 2;
    const int scol = ((lane & 3) * 8) ^ swz32(row16);

    f32x4 acc[4][4];
#pragma unroll
    for (int mf = 0; mf < 4; ++mf)
#pragma unroll
        for (int nf = 0; nf < 4; ++nf) acc[mf][nf] = (f32x4)0.0f;

    for (int kc = 0; kc < 16; ++kc) {
        const int k0 = kc * 32;
        __syncthreads();
#pragma unroll
        for (int i = 0; i < 2; ++i) {
            int c = wave * 2 + i;
            gload16(a_g + (m0 + c * 16 + row16) * 1024 + k0 + scol, a_s + c * 512);
            gload16(bt_g + (size_t)(n0 + c * 16 + row16) * 512 + k0 + scol, b_s + c * 512);
        }
        __syncthreads();
        bf16x8 a[4], b[4];
#pragma unroll
        for (int mf = 0; mf < 4; ++mf) {
            int row = wm * 64 + mf * 16 + lrow;
            a[mf] = *(const bf16x8*)(a_s + row * 32 + ((lgrp * 8) ^ swz32(row)));
        }
#pragma unroll
        for (int nf = 0; nf < 4; ++nf) {
            int rw = wn * 64 + nf * 16 + lrow;
            b[nf] = *(const bf16x8*)(b_s + rw * 32 + ((lgrp * 8) ^ swz32(rw)));
        }
#pragma unroll
        for (int mf = 0; mf < 4; ++mf)
#pragma unroll
            for (int nf = 0; nf < 4; ++nf)
                acc[mf][nf] = MFMA16(a[mf], b[nf], acc[mf][nf]);
    }

#pragma unroll
    for (int nf = 0; nf < 4; ++nf) {
        int col = n0 + wn * 64 + nf * 16 + lrow;
        float bv = bias[col];
#pragma unroll
        for (int mf = 0; mf < 4; ++mf)
#pragma unroll
            for (int j = 0; j < 4; ++j) {
                size_t row = m0 + wm * 64 + mf * 16 + lgrp * 4 + j;
                out[row * 512 + col] = acc[mf][nf][j] + bv;
            }
    }
}

extern "C" void kernel_launch(void* const* d_in, const int* in_sizes, int n_in,
                              void* d_out, int out_size, void* d_ws, size_t ws_size,
                              hipStream_t stream) {
    const float* x      = (const float*)d_in[0];
    const float* adj    = (const float*)d_in[1];
    const float* qkv_w  = (const float*)d_in[2];
    const float* qkv_b  = (const float*)d_in[3];
    const float* proj_w = (const float*)d_in[4];
    const float* proj_b = (const float*)d_in[5];
    float* out = (float*)d_out;

    // ws: qk_ws 134.2MB | vt_ws 67.1MB | qkv_wt 1.5MB | proj_wt 0.5MB
    bf16_t* qk_ws   = (bf16_t*)d_ws;
    bf16_t* vt_ws   = qk_ws + (size_t)NTOK * 1024;
    bf16_t* qkv_wt  = vt_ws + (size_t)4096 * 64 * 128;
    bf16_t* proj_wt = qkv_wt + 1536 * 512;
    // x-bf16 lives in d_out (64MB of its 128MB); proj overwrites d_out last.
    bf16_t* xbf = (bf16_t*)d_out;

    prep_kernel<<<3072, 256, 0, stream>>>(qkv_w, proj_w, qkv_wt, proj_wt);
    prep_x_kernel<<<NTOK * ED / 8 / 256, 256, 0, stream>>>(x, xbf);
    qkv_gemm_kernel<<<6144, 256, 0, stream>>>(xbf, qkv_wt, qkv_b, qk_ws, vt_ws);
    attn_kernel<<<4096, 512, 0, stream>>>(qk_ws, vt_ws, adj);
    proj_kernel<<<2048, 256, 0, stream>>>(qk_ws, proj_wt, proj_b, out);
}

// Round 8
// 304.472 us; speedup vs baseline: 1.1997x; 1.0420x over previous
//
#include <hip/hip_runtime.h>

typedef __bf16 bf16_t;
typedef __bf16 bf16x8 __attribute__((ext_vector_type(8)));
typedef float f32x4 __attribute__((ext_vector_type(4)));

#define MFMA16(a, b, c) __builtin_amdgcn_mfma_f32_16x16x32_bf16(a, b, c, 0, 0, 0)

#define F_W 128
#define ED 512
#define NH 8
#define HD 64
#define B_NW 512
#define NTOK 65536

typedef const __attribute__((address_space(1))) void gvoid_t;
typedef __attribute__((address_space(3))) void lvoid_t;
__device__ __forceinline__ void gload16(const void* g, void* l) {
    __builtin_amdgcn_global_load_lds((gvoid_t*)g, (lvoid_t*)l, 16, 0, 0);
}

// swizzle for [row][32] bf16 tiles (row stride 64B = 16 banks):
// even/odd rows split bank halves; spread row-pairs over the 4 16B slots.
__device__ __forceinline__ int swz32(int row) { return ((row >> 1) & 3) << 3; }

// ---------------- prep: weights -> bf16 transposed --------------------------
__global__ __launch_bounds__(256) void prep_kernel(
    const float* __restrict__ qkv_w,   // [512][1536]
    const float* __restrict__ proj_w,  // [512][512]
    bf16_t* __restrict__ qkv_wt,       // [1536][512]
    bf16_t* __restrict__ proj_wt) {    // [512][512]
    int idx = blockIdx.x * 256 + threadIdx.x;
    if (idx < 1536 * 512) {
        int n = idx >> 9, k = idx & 511;
        qkv_wt[idx] = (bf16_t)qkv_w[k * 1536 + n];
    }
    if (idx < 512 * 512) {
        int n = idx >> 9, k = idx & 511;
        proj_wt[idx] = (bf16_t)proj_w[k * 512 + n];
    }
}

// ---------------- prep_x: x fp32 -> bf16 (into d_out scratch) ---------------
__global__ __launch_bounds__(256) void prep_x_kernel(
    const float* __restrict__ x, bf16_t* __restrict__ xbf) {
    size_t i = ((size_t)blockIdx.x * 256 + threadIdx.x) * 8;
    float4 v0 = *(const float4*)(x + i);
    float4 v1 = *(const float4*)(x + i + 4);
    bf16x8 o = {(bf16_t)v0.x, (bf16_t)v0.y, (bf16_t)v0.z, (bf16_t)v0.w,
                (bf16_t)v1.x, (bf16_t)v1.y, (bf16_t)v1.z, (bf16_t)v1.w};
    *(bf16x8*)(xbf + i) = o;
}

// ---------------- K2: QKV GEMM [65536,512]x[512,1536] -----------------------
// 128x128 tiles, 2x2 wave grid (wave tile 64x64). XCD-remapped grid.
// 1-barrier-per-kc double-buffered pipeline (T3-minimum): issue next-tile
// global_load_lds, compute current, single __syncthreads (vmcnt drain
// overlapped with the 16 MFMAs). n-tiles 0..3 -> Q (x0.125), 4..7 -> K,
// 8..11 -> V (transposed to vt_ws via LDS bounce).
__global__ __launch_bounds__(256, 4) void qkv_gemm_kernel(
    const bf16_t* __restrict__ xbf,     // [NTOK][512] bf16
    const bf16_t* __restrict__ qkv_wt,  // [1536][512] bf16 (n-major)
    const float* __restrict__ qkv_b,    // [1536]
    bf16_t* qk_ws,                      // [NTOK][1024]  Q(scaled)|K
    bf16_t* vt_ws) {                    // [4096][64][128]  V^T per (w,h)
    __shared__ __align__(16) char sm[32768];
    bf16_t* xb0 = (bf16_t*)sm;              // [128][32] swz
    bf16_t* xb1 = (bf16_t*)(sm + 8192);
    bf16_t* wb0 = (bf16_t*)(sm + 16384);
    bf16_t* wb1 = (bf16_t*)(sm + 24576);
    bf16_t* tb  = (bf16_t*)sm;              // [128][72] epilogue bounce (aliases)

    const int tid = threadIdx.x;
    const int wave = tid >> 6, lane = tid & 63;
    const int lrow = lane & 15, lgrp = lane >> 4;
    const int wm = wave >> 1, wn = wave & 1;
    const int bid = blockIdx.x;
    const int idx = bid >> 3;
    const int mt_l = idx / 12;
    const int nt = idx - mt_l * 12;
    const int mtile = (bid & 7) * 64 + mt_l;   // == window index
    const size_t m0 = (size_t)mtile * 128;
    const int n0 = nt * 128;

    // staging: 1KB chunk = 16 rows x 32 bf16; lane -> row lane>>2, seg lane&3
    const int row16 = lane >> 2;
    const int scol = ((lane & 3) * 8) ^ swz32(row16);  // preswizzled source col

    f32x4 acc[4][4];
#pragma unroll
    for (int mf = 0; mf < 4; ++mf)
#pragma unroll
        for (int nf = 0; nf < 4; ++nf) acc[mf][nf] = (f32x4)0.0f;

    // prologue: stage tile 0
#pragma unroll
    for (int i = 0; i < 2; ++i) {
        int c = wave * 2 + i;
        gload16(xbf + (m0 + c * 16 + row16) * 512 + scol, xb0 + c * 512);
        gload16(qkv_wt + (size_t)(n0 + c * 16 + row16) * 512 + scol, wb0 + c * 512);
    }
    __syncthreads();

#pragma unroll 2
    for (int kc = 0; kc < 16; ++kc) {
        bf16_t* xc = (kc & 1) ? xb1 : xb0;
        bf16_t* wc = (kc & 1) ? wb1 : wb0;
        bf16_t* xn = (kc & 1) ? xb0 : xb1;
        bf16_t* wn_ = (kc & 1) ? wb0 : wb1;
        // 1. issue next-tile loads (in flight during compute)
        if (kc < 15) {
            const int k1 = (kc + 1) * 32;
#pragma unroll
            for (int i = 0; i < 2; ++i) {
                int c = wave * 2 + i;
                gload16(xbf + (m0 + c * 16 + row16) * 512 + k1 + scol, xn + c * 512);
                gload16(qkv_wt + (size_t)(n0 + c * 16 + row16) * 512 + k1 + scol, wn_ + c * 512);
            }
        }
        // 2. compute current tile
        bf16x8 a[4], b[4];
#pragma unroll
        for (int mf = 0; mf < 4; ++mf) {
            int row = wm * 64 + mf * 16 + lrow;
            a[mf] = *(const bf16x8*)(xc + row * 32 + ((lgrp * 8) ^ swz32(row)));
        }
#pragma unroll
        for (int nf = 0; nf < 4; ++nf) {
            int rw = wn * 64 + nf * 16 + lrow;
            b[nf] = *(const bf16x8*)(wc + rw * 32 + ((lgrp * 8) ^ swz32(rw)));
        }
#pragma unroll
        for (int mf = 0; mf < 4; ++mf)
#pragma unroll
            for (int nf = 0; nf < 4; ++nf)
                acc[mf][nf] = MFMA16(a[mf], b[nf], acc[mf][nf]);
        // 3. single barrier per tile (drains this wave's vmcnt+lgkmcnt)
        __syncthreads();
    }

    if (nt < 8) {
        // Q or K tile: bias, scale Q, row-major bf16 to qk_ws
        const float scale = (nt < 4) ? 0.125f : 1.0f;
#pragma unroll
        for (int nf = 0; nf < 4; ++nf) {
            int col = n0 + wn * 64 + nf * 16 + lrow;   // [0,1024)
            float bv = qkv_b[col];
#pragma unroll
            for (int mf = 0; mf < 4; ++mf)
#pragma unroll
                for (int j = 0; j < 4; ++j) {
                    int r = wm * 64 + mf * 16 + lgrp * 4 + j;
                    qk_ws[(m0 + r) * 1024 + col] =
                        (bf16_t)((acc[mf][nf][j] + bv) * scale);
                }
        }
    } else {
        // V tile = heads (nt-8)*2 + {0,1}; wave's wn selects the head half.
#pragma unroll
        for (int hh = 0; hh < 2; ++hh) {
            int h = (nt - 8) * 2 + hh;
            __syncthreads();   // prior sm reads complete
            if (wn == hh) {
#pragma unroll
                for (int nf = 0; nf < 4; ++nf) {
                    int d = nf * 16 + lrow;            // [0,64)
                    float bv = qkv_b[n0 + hh * 64 + d];
#pragma unroll
                    for (int mf = 0; mf < 4; ++mf)
#pragma unroll
                        for (int j = 0; j < 4; ++j) {
                            int r = wm * 64 + mf * 16 + lgrp * 4 + j;
                            tb[r * 72 + d] = (bf16_t)(acc[mf][nf][j] + bv);
                        }
                }
            }
            __syncthreads();
            // transpose-read, coalesced write: vt_ws[(mtile*8+h)][d][k]
            {
                int d = tid & 63;
                int kh = tid >> 6;                     // k range kh*32
                bf16_t* outp = vt_ws + ((size_t)(mtile * 8 + h) * 64 + d) * 128 + kh * 32;
#pragma unroll
                for (int o = 0; o < 4; ++o) {
                    bf16x8 v;
#pragma unroll
                    for (int e = 0; e < 8; ++e)
                        v[e] = tb[(kh * 32 + o * 8 + e) * 72 + d];
                    *(bf16x8*)(outp + o * 8) = v;
                }
            }
        }
    }
}

// ---------------- K3: attention-only, block=(window,head), 512 thr ----------
__global__ __launch_bounds__(512, 4) void attn_kernel(
    bf16_t* qk_ws,                      // [NTOK][1024] (Q|K; O -> Q cols)
    const bf16_t* __restrict__ vt_ws,   // [4096][64][128]
    const float* __restrict__ adj) {    // [8][8][128][128]
    __shared__ __align__(16) char sm[32768];
    bf16_t* k_lds  = (bf16_t*)sm;             // [128][64]
    bf16_t* vt_lds = (bf16_t*)(sm + 16384);   // [64][128]
    bf16_t* pbuf   = (bf16_t*)sm;             // [128][40] (aliases k after B)

    const int tid = threadIdx.x;
    const int wave = tid >> 6, lane = tid & 63;
    const int lrow = lane & 15, lgrp = lane >> 4;
    const int bid = blockIdx.x;
    const int w = (bid & 7) * 64 + (bid >> 6);
    const int h = (bid >> 3) & 7;
    const int bidx = bid & 7;

    bf16_t* qrow = qk_ws + (size_t)w * 128 * 1024;

    {
        const int krow_l = lane >> 3;
        const int kcol_l = ((lane & 7) * 8) ^ ((krow_l & 7) << 3);
#pragma unroll
        for (int i = 0; i < 2; ++i) {
            int c = wave * 2 + i;
            gload16(qrow + (size_t)(c * 8 + krow_l) * 1024 + 512 + h * 64 + kcol_l,
                    k_lds + c * 512);
        }
    }
    {
        const bf16_t* vtb = vt_ws + (size_t)(w * 8 + h) * 64 * 128;
        const int vrow_l = lane >> 4;
#pragma unroll
        for (int i = 0; i < 2; ++i) {
            int c = wave * 2 + i;
            int d = c * 4 + vrow_l;
            int vcol = ((lane & 15) * 8) ^ ((d & 7) << 3);
            gload16(vtb + (size_t)d * 128 + vcol, vt_lds + c * 512);
        }
    }
    bf16x8 aq[2];
    {
        int row = wave * 16 + lrow;
#pragma unroll
        for (int kb = 0; kb < 2; ++kb)
            aq[kb] = *(const bf16x8*)(qrow + (size_t)row * 1024 + h * 64 + kb * 32 + lgrp * 8);
    }
    __syncthreads();

    f32x4 sacc[8];
#pragma unroll
    for (int nf = 0; nf < 8; ++nf) sacc[nf] = (f32x4)0.0f;
#pragma unroll
    for (int kb = 0; kb < 2; ++kb) {
        bf16x8 b[8];
#pragma unroll
        for (int nf = 0; nf < 8; ++nf) {
            int row = nf * 16 + lrow;
            b[nf] = *(const bf16x8*)(k_lds + row * 64 + ((kb * 32 + lgrp * 8) ^ ((row & 7) << 3)));
        }
#pragma unroll
        for (int nf = 0; nf < 8; ++nf)
            sacc[nf] = MFMA16(aq[kb], b[nf], sacc[nf]);
    }

    const float* mbase = adj + ((size_t)(bidx * NH + h)) * F_W * F_W;
#pragma unroll
    for (int j = 0; j < 4; ++j) {
        int row = wave * 16 + lgrp * 4 + j;
        const float* mrow = mbase + (size_t)row * F_W;
        float mx = -1e30f;
#pragma unroll
        for (int nf = 0; nf < 8; ++nf) {
            sacc[nf][j] += mrow[nf * 16 + lrow];
            mx = fmaxf(mx, sacc[nf][j]);
        }
#pragma unroll
        for (int d = 1; d < 16; d <<= 1) mx = fmaxf(mx, __shfl_xor(mx, d));
        float sum = 0.f;
#pragma unroll
        for (int nf = 0; nf < 8; ++nf) {
            float p = exp2f((sacc[nf][j] - mx) * 1.44269504f);
            sacc[nf][j] = p;
            sum += p;
        }
#pragma unroll
        for (int d = 1; d < 16; d <<= 1) sum += __shfl_xor(sum, d);
        float r = 1.0f / sum;
#pragma unroll
        for (int nf = 0; nf < 8; ++nf) sacc[nf][j] *= r;
    }
    __syncthreads();

    f32x4 oacc[4];
#pragma unroll
    for (int nf = 0; nf < 4; ++nf) oacc[nf] = (f32x4)0.0f;

#pragma unroll
    for (int kb = 0; kb < 4; ++kb) {
#pragma unroll
        for (int nn = 0; nn < 2; ++nn) {
            int nf = kb * 2 + nn;
            int kk = nn * 16 + lrow;
#pragma unroll
            for (int j = 0; j < 4; ++j) {
                int r = wave * 16 + lgrp * 4 + j;
                pbuf[r * 40 + kk] = (bf16_t)(sacc[nf][j]);
            }
        }
        __syncthreads();
        bf16x8 a = *(const bf16x8*)(pbuf + (wave * 16 + lrow) * 40 + lgrp * 8);
        bf16x8 b[4];
#pragma unroll
        for (int nf = 0; nf < 4; ++nf) {
            int d = nf * 16 + lrow;
            b[nf] = *(const bf16x8*)(vt_lds + d * 128 + ((kb * 32 + lgrp * 8) ^ ((d & 7) << 3)));
        }
#pragma unroll
        for (int nf = 0; nf < 4; ++nf)
            oacc[nf] = MFMA16(a, b[nf], oacc[nf]);
        __syncthreads();
    }

#pragma unroll
    for (int nf = 0; nf < 4; ++nf) {
        int ocol = h * 64 + nf * 16 + lrow;
#pragma unroll
        for (int j = 0; j < 4; ++j) {
            int r = wave * 16 + lgrp * 4 + j;
            qrow[(size_t)r * 1024 + ocol] = (bf16_t)oacc[nf][j];
        }
    }
}

// ---------------- K4: output projection [65536,512]@[512,512]+b -------------
// 1-barrier double-buffered pipeline, same as K2.
__global__ __launch_bounds__(256, 4) void proj_kernel(
    const bf16_t* __restrict__ a_g,   // [NTOK][1024] (cols 0..511 = O)
    const bf16_t* __restrict__ bt_g,  // proj_wt [512][512] (n-major)
    const float* __restrict__ bias,   // [512]
    float* __restrict__ out) {        // [NTOK][512] fp32
    __shared__ __align__(16) char sm_[32768];
    bf16_t* ab0 = (bf16_t*)sm_;
    bf16_t* ab1 = (bf16_t*)(sm_ + 8192);
    bf16_t* bb0 = (bf16_t*)(sm_ + 16384);
    bf16_t* bb1 = (bf16_t*)(sm_ + 24576);
    const int tid = threadIdx.x;
    const int wave = tid >> 6, lane = tid & 63;
    const int lrow = lane & 15, lgrp = lane >> 4;
    const int wm = wave >> 1, wn = wave & 1;
    const int bid = blockIdx.x;                        // [0,2048)
    const int mtile = (bid & 7) * 64 + (bid >> 5);
    const int ntile = (bid >> 3) & 3;
    const size_t m0 = (size_t)mtile * 128;
    const int n0 = ntile * 128;
    const int row16 = lane >> 2;
    const int scol = ((lane & 3) * 8) ^ swz32(row16);

    f32x4 acc[4][4];
#pragma unroll
    for (int mf = 0; mf < 4; ++mf)
#pragma unroll
        for (int nf = 0; nf < 4; ++nf) acc[mf][nf] = (f32x4)0.0f;

#pragma unroll
    for (int i = 0; i < 2; ++i) {
        int c = wave * 2 + i;
        gload16(a_g + (m0 + c * 16 + row16) * 1024 + scol, ab0 + c * 512);
        gload16(bt_g + (size_t)(n0 + c * 16 + row16) * 512 + scol, bb0 + c * 512);
    }
    __syncthreads();

#pragma unroll 2
    for (int kc = 0; kc < 16; ++kc) {
        bf16_t* ac = (kc & 1) ? ab1 : ab0;
        bf16_t* bc = (kc & 1) ? bb1 : bb0;
        bf16_t* an = (kc & 1) ? ab0 : ab1;
        bf16_t* bn = (kc & 1) ? bb0 : bb1;
        if (kc < 15) {
            const int k1 = (kc + 1) * 32;
#pragma unroll
            for (int i = 0; i < 2; ++i) {
                int c = wave * 2 + i;
                gload16(a_g + (m0 + c * 16 + row16) * 1024 + k1 + scol, an + c * 512);
                gload16(bt_g + (size_t)(n0 + c * 16 + row16) * 512 + k1 + scol, bn + c * 512);
            }
        }
        bf16x8 a[4], b[4];
#pragma unroll
        for (int mf = 0; mf < 4; ++mf) {
            int row = wm * 64 + mf * 16 + lrow;
            a[mf] = *(const bf16x8*)(ac + row * 32 + ((lgrp * 8) ^ swz32(row)));
        }
#pragma unroll
        for (int nf = 0; nf < 4; ++nf) {
            int rw = wn * 64 + nf * 16 + lrow;
            b[nf] = *(const bf16x8*)(bc + rw * 32 + ((lgrp * 8) ^ swz32(rw)));
        }
#pragma unroll
        for (int mf = 0; mf < 4; ++mf)
#pragma unroll
            for (int nf = 0; nf < 4; ++nf)
                acc[mf][nf] = MFMA16(a[mf], b[nf], acc[mf][nf]);
        __syncthreads();
    }

#pragma unroll
    for (int nf = 0; nf < 4; ++nf) {
        int col = n0 + wn * 64 + nf * 16 + lrow;
        float bv = bias[col];
#pragma unroll
        for (int mf = 0; mf < 4; ++mf)
#pragma unroll
            for (int j = 0; j < 4; ++j) {
                size_t row = m0 + wm * 64 + mf * 16 + lgrp * 4 + j;
                out[row * 512 + col] = acc[mf][nf][j] + bv;
            }
    }
}

extern "C" void kernel_launch(void* const* d_in, const int* in_sizes, int n_in,
                              void* d_out, int out_size, void* d_ws, size_t ws_size,
                              hipStream_t stream) {
    const float* x      = (const float*)d_in[0];
    const float* adj    = (const float*)d_in[1];
    const float* qkv_w  = (const float*)d_in[2];
    const float* qkv_b  = (const float*)d_in[3];
    const float* proj_w = (const float*)d_in[4];
    const float* proj_b = (const float*)d_in[5];
    float* out = (float*)d_out;

    // ws: qk_ws 134.2MB | vt_ws 67.1MB | qkv_wt 1.5MB | proj_wt 0.5MB
    bf16_t* qk_ws   = (bf16_t*)d_ws;
    bf16_t* vt_ws   = qk_ws + (size_t)NTOK * 1024;
    bf16_t* qkv_wt  = vt_ws + (size_t)4096 * 64 * 128;
    bf16_t* proj_wt = qkv_wt + 1536 * 512;
    // x-bf16 lives in d_out (64MB of its 128MB); proj overwrites d_out last.
    bf16_t* xbf = (bf16_t*)d_out;

    prep_kernel<<<3072, 256, 0, stream>>>(qkv_w, proj_w, qkv_wt, proj_wt);
    prep_x_kernel<<<NTOK * ED / 8 / 256, 256, 0, stream>>>(x, xbf);
    qkv_gemm_kernel<<<6144, 256, 0, stream>>>(xbf, qkv_wt, qkv_b, qk_ws, vt_ws);
    attn_kernel<<<4096, 512, 0, stream>>>(qk_ws, vt_ws, adj);
    proj_kernel<<<2048, 256, 0, stream>>>(qk_ws, proj_wt, proj_b, out);
}